// Round 1
// 242.309 us; speedup vs baseline: 1.0777x; 1.0777x over previous
//
#include <hip/hip_runtime.h>

#define IN_DIM 128
#define HID 64
#define MAXC 400            // >= ceil(N/256); N=100000 -> 391 coarse buckets
#define MAXB 256            // >= NBLK = ceil(E/EPB) = 196
#define EPB 8192
#define DPT 1024            // degplace threads per block
#define G1CAP 6144          // LDS floats for k_gather1 staging (E[block]=4096, +32 sigma)

// ---- bf16 helpers (RNE) ----
static __device__ __forceinline__ unsigned short f2bf(float f) {
    unsigned u = __float_as_uint(f);
    u += 0x7FFF + ((u >> 16) & 1);
    return (unsigned short)(u >> 16);
}

typedef short bf16x8 __attribute__((ext_vector_type(8)));
typedef float f32x4 __attribute__((ext_vector_type(4)));

// ---- pass 0: per-block bucket histogram -> hmat[blk][cb] (coalesced row) ----
__global__ __launch_bounds__(256) void k_hist2(const int* __restrict__ dst,
                                               int* __restrict__ hmat, int E, int NC) {
    __shared__ int h[MAXC];
    int tid = threadIdx.x, blk = blockIdx.x;
    for (int i = tid; i < NC; i += 256) h[i] = 0;
    __syncthreads();
    int e0 = blk * EPB, e1 = min(e0 + EPB, E);
    for (int e = e0 + tid; e < e1; e += 256) atomicAdd(&h[dst[e] >> 8], 1);
    __syncthreads();
    for (int i = tid; i < NC; i += 256) hmat[blk * MAXC + i] = h[i];
}

// ---- per-bucket exclusive scan across blocks (in-place) + bucket totals ----
__global__ __launch_bounds__(256) void k_bktscan(int* __restrict__ hmat,
                                                 int* __restrict__ bktTotal,
                                                 int NBLK, int NC) {
    __shared__ int tmp[256];
    int cb = blockIdx.x;
    int t = threadIdx.x;
    int v = (t < NBLK) ? hmat[t * MAXC + cb] : 0;
    tmp[t] = v;
    __syncthreads();
    for (int off = 1; off < 256; off <<= 1) {
        int a = (t >= off) ? tmp[t - off] : 0;
        __syncthreads();
        tmp[t] += a;
        __syncthreads();
    }
    if (t < NBLK) hmat[t * MAXC + cb] = tmp[t] - v;   // exclusive prefix within bucket
    if (t == 255) bktTotal[cb] = tmp[255];
}

// ---- single-block scan over bucket totals -> coarseStart ----
__global__ __launch_bounds__(512) void k_cscan(const int* __restrict__ bktTotal,
                                               int* __restrict__ coarseStart,
                                               int* __restrict__ rowStart,
                                               int NC, int N, int E) {
    __shared__ int tmp[512];
    int t = threadIdx.x;
    int v = (t < NC) ? bktTotal[t] : 0;
    tmp[t] = v;
    __syncthreads();
    for (int off = 1; off < 512; off <<= 1) {
        int a = (t >= off) ? tmp[t - off] : 0;
        __syncthreads();
        tmp[t] += a;
        __syncthreads();
    }
    int excl = tmp[t] - v;
    if (t < NC) coarseStart[t] = excl;
    if (t == NC - 1) coarseStart[NC] = excl + v;   // == E
    if (t == 0) rowStart[N] = E;
}

// ---- pass 1: deterministic placement into dense coarse-sorted array ----
// tmp1[pos] = src | (dloc << 17); no global atomics.
__global__ __launch_bounds__(256) void k_part1(const int* __restrict__ src,
                                               const int* __restrict__ dst,
                                               const int* __restrict__ hmat,
                                               const int* __restrict__ coarseStart,
                                               int* __restrict__ tmp1,
                                               int E, int NC) {
    __shared__ int bcnt[MAXC];
    __shared__ int bbase[MAXC];
    int tid = threadIdx.x, blk = blockIdx.x;
    for (int i = tid; i < NC; i += 256) {
        bcnt[i] = 0;
        bbase[i] = coarseStart[i] + hmat[blk * MAXC + i];   // coalesced
    }
    __syncthreads();
    int e0 = blk * EPB, e1 = min(e0 + EPB, E);
    for (int e = e0 + tid; e < e1; e += 256) {
        int s = src[e], d = dst[e];
        int cb = d >> 8;
        int slot = bbase[cb] + atomicAdd(&bcnt[cb], 1);
        tmp1[slot] = s | ((d & 255) << 17);
    }
}

// ---- pass 2 (fused): per-bucket degree->dis/rowStart, then place into CSR ----
// esrc holds BYTE offsets (s*128) for the gather's dword addressing.
__global__ __launch_bounds__(DPT) void k_degplace(const int* __restrict__ tmp1,
                                                  const int* __restrict__ coarseStart,
                                                  float* __restrict__ dis,
                                                  int* __restrict__ rowStart,
                                                  int* __restrict__ esrc, int N) {
    __shared__ int hist[256];
    __shared__ int scn[256];
    __shared__ int cur[256];
    int tid = threadIdx.x;
    int cb = blockIdx.x;
    int node0 = cb << 8;
    const int r0 = coarseStart[cb], r1 = coarseStart[cb + 1];
    if (tid < 256) hist[tid] = 0;
    __syncthreads();
    for (int i = r0 + tid; i < r1; i += DPT)
        atomicAdd(&hist[((unsigned)tmp1[i]) >> 17], 1);
    __syncthreads();
    int v = 0;
    if (tid < 256) { v = hist[tid]; scn[tid] = v; }
    __syncthreads();
    for (int off = 1; off < 256; off <<= 1) {
        int a = 0;
        if (tid < 256 && tid >= off) a = scn[tid - off];
        __syncthreads();
        if (tid < 256) scn[tid] += a;
        __syncthreads();
    }
    if (tid < 256) {
        int myStart = r0 + scn[tid] - v;
        cur[tid] = myStart;
        int node = node0 + tid;
        if (node < N) {
            dis[node] = rsqrtf((float)v + 1.0f);
            rowStart[node] = myStart;
        }
    }
    __syncthreads();
    for (int i = r0 + tid; i < r1; i += DPT) {
        int pk = tmp1[i];
        int dl = ((unsigned)pk) >> 17;
        int pos = atomicAdd(&cur[dl], 1);
        esrc[pos] = (pk & 0x1FFFF) << 7;     // byte offset of bf16 row
    }
}

// ------- MFMA transform: Hbs[N,64] = bf16( (X[N,K] @ W[K,64]) * dis[row] ) -------
template <int K, typename T>
__global__ __launch_bounds__(256) void k_mmx(const T* __restrict__ X,
                                             const float* __restrict__ W,
                                             const float* __restrict__ dis,
                                             unsigned short* __restrict__ Hbs, int N) {
    constexpr int WP = K + 8;
    __shared__ unsigned short Wt[64 * WP];
    const int tid = threadIdx.x;
    for (int i = tid; i < K * 64; i += 256) {
        int k = i >> 6, n = i & 63;
        Wt[n * WP + k] = f2bf(W[i]);
    }
    __syncthreads();
    const int lane = tid & 63;
    const int m16 = lane & 15;
    const int quad = lane >> 4;
    const int rowBase = blockIdx.x * 64 + (tid >> 6) * 16;
    const int rowc = min(rowBase + m16, N - 1);

    f32x4 acc0 = {0.f, 0.f, 0.f, 0.f};
    f32x4 acc1 = acc0, acc2 = acc0, acc3 = acc0;
    const T* xrow = X + (size_t)rowc * K;
#pragma unroll
    for (int k0 = 0; k0 < K; k0 += 32) {
        bf16x8 af;
        if constexpr (sizeof(T) == 4) {
            const float* xp = (const float*)xrow + k0 + quad * 8;
            float4 xa = *(const float4*)xp;
            float4 xb = *(const float4*)(xp + 4);
            af[0] = (short)f2bf(xa.x); af[1] = (short)f2bf(xa.y);
            af[2] = (short)f2bf(xa.z); af[3] = (short)f2bf(xa.w);
            af[4] = (short)f2bf(xb.x); af[5] = (short)f2bf(xb.y);
            af[6] = (short)f2bf(xb.z); af[7] = (short)f2bf(xb.w);
        } else {
            af = *(const bf16x8*)((const unsigned short*)xrow + k0 + quad * 8);
        }
        const unsigned short* wp = &Wt[m16 * WP + k0 + quad * 8];
        bf16x8 b0 = *(const bf16x8*)(wp);
        bf16x8 b1 = *(const bf16x8*)(wp + 16 * WP);
        bf16x8 b2 = *(const bf16x8*)(wp + 32 * WP);
        bf16x8 b3 = *(const bf16x8*)(wp + 48 * WP);
        acc0 = __builtin_amdgcn_mfma_f32_16x16x32_bf16(af, b0, acc0, 0, 0, 0);
        acc1 = __builtin_amdgcn_mfma_f32_16x16x32_bf16(af, b1, acc1, 0, 0, 0);
        acc2 = __builtin_amdgcn_mfma_f32_16x16x32_bf16(af, b2, acc2, 0, 0, 0);
        acc3 = __builtin_amdgcn_mfma_f32_16x16x32_bf16(af, b3, acc3, 0, 0, 0);
    }
#pragma unroll
    for (int reg = 0; reg < 4; ++reg) {
        int r = rowBase + quad * 4 + reg;
        if (r < N) {
            float dsc = dis[r];
            unsigned short* hp = Hbs + (size_t)r * 64 + m16;
            hp[0]  = f2bf(acc0[reg] * dsc);
            hp[16] = f2bf(acc1[reg] * dsc);
            hp[32] = f2bf(acc2[reg] * dsc);
            hp[48] = f2bf(acc3[reg] * dsc);
        }
    }
}

// ------- gather-aggregate: wave per 4 nodes, dwordx2 per lane, 4 edges/instr ---
// lane = c (0..15, 8B chunk of 128B row) + sub (0..3, edge slot / node slot)
// MODE 1: out = relu row, stored bf16 (feeds bf16 mmx)
// MODE 2: relu row, dot with W3, write colS[i] = dot*dis and out[i] = dot*dis^2 + b3

#define ACCADD(A, D)                                                           \
    {                                                                          \
        A.x += __uint_as_float((D).x << 16);                                   \
        A.y += __uint_as_float((D).x & 0xFFFF0000u);                           \
        A.z += __uint_as_float((D).y << 16);                                   \
        A.w += __uint_as_float((D).y & 0xFFFF0000u);                           \
    }

#define GNODE4(ACC, RA, RB)                                                    \
    {                                                                          \
        int j0 = max(RA - base, 0);                                            \
        int j1 = min(RB - base, cnt);                                          \
        int j = j0;                                                            \
        for (; j + 16 <= j1; j += 16) {                                        \
            unsigned o0 = __shfl(eoff, j + sub, 64);                           \
            unsigned o1 = __shfl(eoff, j + 4 + sub, 64);                       \
            unsigned o2 = __shfl(eoff, j + 8 + sub, 64);                       \
            unsigned o3 = __shfl(eoff, j + 12 + sub, 64);                      \
            uint2 q0 = *(const uint2*)(hb + o0);                               \
            uint2 q1 = *(const uint2*)(hb + o1);                               \
            uint2 q2 = *(const uint2*)(hb + o2);                               \
            uint2 q3 = *(const uint2*)(hb + o3);                               \
            ACCADD(ACC, q0) ACCADD(ACC, q1) ACCADD(ACC, q2) ACCADD(ACC, q3)    \
        }                                                                      \
        if (j + 8 <= j1) {                                                     \
            unsigned o0 = __shfl(eoff, j + sub, 64);                           \
            unsigned o1 = __shfl(eoff, j + 4 + sub, 64);                       \
            uint2 q0 = *(const uint2*)(hb + o0);                               \
            uint2 q1 = *(const uint2*)(hb + o1);                               \
            ACCADD(ACC, q0) ACCADD(ACC, q1)                                    \
            j += 8;                                                            \
        }                                                                      \
        if (j + 4 <= j1) {                                                     \
            unsigned o0 = __shfl(eoff, j + sub, 64);                           \
            uint2 q0 = *(const uint2*)(hb + o0);                               \
            ACCADD(ACC, q0)                                                    \
            j += 4;                                                            \
        }                                                                      \
        if (j < j1) {                                                          \
            int idx = j + sub;                                                 \
            bool vld = idx < j1;                                               \
            unsigned o0 = __shfl(eoff, vld ? idx : j0, 64);                    \
            uint2 q0 = *(const uint2*)(hb + o0);                               \
            if (!vld) { q0.x = 0u; q0.y = 0u; }                                \
            ACCADD(ACC, q0)                                                    \
        }                                                                      \
    }

#define REDX(A)                                                                \
    {                                                                          \
        A.x += __shfl_xor(A.x, 16, 64); A.y += __shfl_xor(A.y, 16, 64);        \
        A.z += __shfl_xor(A.z, 16, 64); A.w += __shfl_xor(A.w, 16, 64);        \
        A.x += __shfl_xor(A.x, 32, 64); A.y += __shfl_xor(A.y, 32, 64);        \
        A.z += __shfl_xor(A.z, 32, 64); A.w += __shfl_xor(A.w, 32, 64);        \
    }

template <int MODE>
__global__ __launch_bounds__(256) void k_gather64(const unsigned short* __restrict__ Hbs,
                                                  const int* __restrict__ esrc,
                                                  const int* __restrict__ rowStart,
                                                  const float* __restrict__ dis,
                                                  const float* __restrict__ b,
                                                  unsigned short* __restrict__ outB,
                                                  const float* __restrict__ W3,
                                                  const float* __restrict__ b3,
                                                  float* __restrict__ colS,
                                                  float* __restrict__ outF,
                                                  int N) {
    int lane = threadIdx.x & 63;
    int c = lane & 15;          // 8B chunk of the 128B row
    int sub = lane >> 4;        // edge slot in loads; node slot in epilogue
    int wave = (blockIdx.x * 256 + threadIdx.x) >> 6;
    int g0 = wave * 4;
    if (g0 >= N) return;
    const char* hb = (const char*)Hbs + c * 8;

    int rb = rowStart[min(g0 + lane, N)];
    int R0 = __shfl(rb, 0, 64), R1 = __shfl(rb, 1, 64);
    int R2 = __shfl(rb, 2, 64), R3 = __shfl(rb, 3, 64);
    int R4 = __shfl(rb, 4, 64);

    // self-loop seed: quarter s seeds node g0+s (counted once in the reduce)
    float4 a0 = {0.f, 0.f, 0.f, 0.f}, a1 = a0, a2 = a0, a3 = a0;
    {
        int nself = min(g0 + sub, N - 1);
        uint2 sd = *(const uint2*)(hb + ((size_t)nself << 7));
        float4 sf;
        sf.x = __uint_as_float(sd.x << 16);
        sf.y = __uint_as_float(sd.x & 0xFFFF0000u);
        sf.z = __uint_as_float(sd.y << 16);
        sf.w = __uint_as_float(sd.y & 0xFFFF0000u);
        if (sub == 0) a0 = sf;
        else if (sub == 1) a1 = sf;
        else if (sub == 2) a2 = sf;
        else a3 = sf;
    }

    for (int base = R0; base < R4; base += 64) {
        int cnt = min(64, R4 - base);
        unsigned eoff = (lane < cnt) ? (unsigned)esrc[base + lane] : 0u;
        GNODE4(a0, R0, R1)
        GNODE4(a1, R1, R2)
        GNODE4(a2, R2, R3)
        GNODE4(a3, R3, R4)
    }

    // merge 4 sub-group partials: every lane ends with full sums for its c
    REDX(a0) REDX(a1) REDX(a2) REDX(a3)

    // each quarter finalizes its own node
    float4 a = a0;
    if (sub == 1) a = a1;
    if (sub == 2) a = a2;
    if (sub == 3) a = a3;
    int node = g0 + sub;
    float ds = dis[min(node, N - 1)];
    float4 bl = ((const float4*)b)[c];
    float4 v;
    v.x = fmaxf(a.x * ds + bl.x, 0.f);
    v.y = fmaxf(a.y * ds + bl.y, 0.f);
    v.z = fmaxf(a.z * ds + bl.z, 0.f);
    v.w = fmaxf(a.w * ds + bl.w, 0.f);

    if (MODE == 1) {
        uint2 pv;
        pv.x = (unsigned)f2bf(v.x) | ((unsigned)f2bf(v.y) << 16);
        pv.y = (unsigned)f2bf(v.z) | ((unsigned)f2bf(v.w) << 16);
        if (node < N) ((uint2*)outB)[(size_t)node * 16 + c] = pv;   // 128B/row coalesced
    } else {
        float4 w3 = ((const float4*)W3)[c];
        float t = v.x * w3.x + v.y * w3.y + v.z * w3.z + v.w * w3.w;
        t += __shfl_xor(t, 1, 64);
        t += __shfl_xor(t, 2, 64);
        t += __shfl_xor(t, 4, 64);
        t += __shfl_xor(t, 8, 64);
        if (c == 0 && node < N) {
            colS[node] = t * ds;
            outF[node] = t * ds * ds + b3[0];
        }
    }
}

// layer-3 aggregation: stage block's colS values in LDS (parallel loads),
// then per-node serial sum out of LDS. out[i] += dis[i] * sum colS[esrc>>7]
__global__ __launch_bounds__(256) void k_gather1(const float* __restrict__ colS,
                                                 const int* __restrict__ esrc,
                                                 const int* __restrict__ rowStart,
                                                 const float* __restrict__ dis,
                                                 float* __restrict__ out, int N) {
    __shared__ float ls[G1CAP];
    int tid = threadIdx.x;
    int n0 = blockIdx.x * 256;
    int nEnd = min(n0 + 256, N);
    int r0 = rowStart[n0];
    int r1 = rowStart[nEnd];
    int cnt = r1 - r0;
    if (cnt <= G1CAP) {
        for (int i = tid; i < cnt; i += 256)
            ls[i] = colS[((unsigned)esrc[r0 + i]) >> 7];
        __syncthreads();
        int n = n0 + tid;
        if (n < N) {
            int a = rowStart[n] - r0, bnd = rowStart[n + 1] - r0;
            float acc = 0.0f;
            for (int e = a; e < bnd; ++e) acc += ls[e];
            out[n] += acc * dis[n];
        }
    } else {   // statistically unreachable fallback
        int n = n0 + tid;
        if (n < N) {
            int a = rowStart[n], bnd = rowStart[n + 1];
            float acc = 0.0f;
            for (int e = a; e < bnd; ++e) acc += colS[((unsigned)esrc[e]) >> 7];
            out[n] += acc * dis[n];
        }
    }
}

extern "C" void kernel_launch(void* const* d_in, const int* in_sizes, int n_in,
                              void* d_out, int out_size, void* d_ws, size_t ws_size,
                              hipStream_t stream) {
    const float* x  = (const float*)d_in[0];
    const int*   ei = (const int*)d_in[1];
    const float* W1 = (const float*)d_in[2];
    const float* b1 = (const float*)d_in[3];
    const float* W2 = (const float*)d_in[4];
    const float* b2 = (const float*)d_in[5];
    const float* W3 = (const float*)d_in[6];
    const float* b3 = (const float*)d_in[7];
    float* out = (float*)d_out;

    const int N = in_sizes[0] / IN_DIM;     // 100000
    const int E = in_sizes[1] / 2;          // 1600000
    const int* src = ei;
    const int* dst = ei + E;
    const int NC = (N + 255) >> 8;          // 391 coarse buckets
    const int NBLK = (E + EPB - 1) / EPB;   // 196 partition blocks

    // ---- workspace layout ----
    char* w = (char*)d_ws;
    auto alloc = [&](size_t bytes) {
        char* p = w;
        w += (bytes + 1023) & ~(size_t)1023;
        return p;
    };
    float*          dis        = (float*)alloc((size_t)N * 4);
    unsigned short* Hbs        = (unsigned short*)alloc((size_t)N * 64 * 2);
    unsigned short* Hb1        = (unsigned short*)alloc((size_t)N * 64 * 2);
    float*          colS       = (float*)alloc((size_t)N * 4);
    int*            rowStart   = (int*)alloc((size_t)(N + 1) * 4);
    int*            bktTotal   = (int*)alloc((size_t)MAXC * 4);
    int*            coarseStart= (int*)alloc((size_t)(MAXC + 1) * 4);
    int*            hmat       = (int*)alloc((size_t)MAXB * MAXC * 4);
    int*            esrc       = (int*)alloc((size_t)E * 4);
    int*            tmp1       = (int*)alloc((size_t)E * 4);

    const int NB_N  = (N + 255) / 256;
    const int NB_MX = (N + 63) / 64;                    // MFMA transform blocks
    const int NB_G4 = ((N + 3) / 4 * 64 + 255) / 256;   // 4 nodes per wave

    // ---- deterministic partition (no global atomics, no memset) ----
    k_hist2<<<NBLK, 256, 0, stream>>>(dst, hmat, E, NC);
    k_bktscan<<<NC, 256, 0, stream>>>(hmat, bktTotal, NBLK, NC);
    k_cscan<<<1, 512, 0, stream>>>(bktTotal, coarseStart, rowStart, NC, N, E);
    k_part1<<<NBLK, 256, 0, stream>>>(src, dst, hmat, coarseStart, tmp1, E, NC);
    k_degplace<<<NC, DPT, 0, stream>>>(tmp1, coarseStart, dis, rowStart, esrc, N);

    // ---- layer 1: mmx fp32->bf16, gather -> bf16 rows ----
    k_mmx<IN_DIM, float><<<NB_MX, 256, 0, stream>>>(x, W1, dis, Hbs, N);
    k_gather64<1><<<NB_G4, 256, 0, stream>>>(Hbs, esrc, rowStart, dis, b1,
                                             Hb1, nullptr, nullptr, nullptr, nullptr, N);

    // ---- layer 2: mmx bf16 input, gather fused with W3 dot ----
    k_mmx<HID, unsigned short><<<NB_MX, 256, 0, stream>>>(Hb1, W2, dis, Hbs, N);
    k_gather64<2><<<NB_G4, 256, 0, stream>>>(Hbs, esrc, rowStart, dis, b2,
                                             nullptr, W3, b3, colS, out, N);

    // ---- layer 3 aggregation ----
    k_gather1<<<NB_N, 256, 0, stream>>>(colS, esrc, rowStart, dis, out, N);
}

// Round 3
// 233.268 us; speedup vs baseline: 1.1194x; 1.0388x over previous
//
#include <hip/hip_runtime.h>

#define IN_DIM 128
#define HID 64
#define MAXC 400            // >= ceil(N/256); N=100000 -> 391 coarse buckets
#define MAXB 512            // >= NBLK = ceil(E/EPB) = 391
#define EPB 4096
#define DPT 512             // degplace threads per block
#define G1CAP 6144          // LDS floats for k_gather1 staging (E[block]=4096, +32 sigma)

// ---- bf16 helpers (RNE) ----
static __device__ __forceinline__ unsigned short f2bf(float f) {
    unsigned u = __float_as_uint(f);
    u += 0x7FFF + ((u >> 16) & 1);
    return (unsigned short)(u >> 16);
}

typedef short bf16x8 __attribute__((ext_vector_type(8)));
typedef float f32x4 __attribute__((ext_vector_type(4)));

// ---- pass 0: per-block bucket histogram -> hmat[blk][cb] (coalesced row) ----
__global__ __launch_bounds__(256) void k_hist2(const int* __restrict__ dst,
                                               int* __restrict__ hmat, int E, int NC) {
    __shared__ int h[MAXC];
    int tid = threadIdx.x, blk = blockIdx.x;
    for (int i = tid; i < NC; i += 256) h[i] = 0;
    __syncthreads();
    int e0 = blk * EPB, e1 = min(e0 + EPB, E);
    for (int e = e0 + tid; e < e1; e += 256) atomicAdd(&h[dst[e] >> 8], 1);
    __syncthreads();
    for (int i = tid; i < NC; i += 256) hmat[blk * MAXC + i] = h[i];
}

// ---- per-bucket exclusive scan across blocks (in-place) + bucket totals ----
__global__ __launch_bounds__(512) void k_bktscan(int* __restrict__ hmat,
                                                 int* __restrict__ bktTotal,
                                                 int NBLK, int NC) {
    __shared__ int tmp[512];
    int cb = blockIdx.x;
    int t = threadIdx.x;
    int v = (t < NBLK) ? hmat[t * MAXC + cb] : 0;
    tmp[t] = v;
    __syncthreads();
    for (int off = 1; off < 512; off <<= 1) {
        int a = (t >= off) ? tmp[t - off] : 0;
        __syncthreads();
        tmp[t] += a;
        __syncthreads();
    }
    if (t < NBLK) hmat[t * MAXC + cb] = tmp[t] - v;   // exclusive prefix within bucket
    if (t == 511) bktTotal[cb] = tmp[511];
}

// ---- single-block scan over bucket totals -> coarseStart ----
__global__ __launch_bounds__(512) void k_cscan(const int* __restrict__ bktTotal,
                                               int* __restrict__ coarseStart,
                                               int* __restrict__ rowStart,
                                               int NC, int N, int E) {
    __shared__ int tmp[512];
    int t = threadIdx.x;
    int v = (t < NC) ? bktTotal[t] : 0;
    tmp[t] = v;
    __syncthreads();
    for (int off = 1; off < 512; off <<= 1) {
        int a = (t >= off) ? tmp[t - off] : 0;
        __syncthreads();
        tmp[t] += a;
        __syncthreads();
    }
    int excl = tmp[t] - v;
    if (t < NC) coarseStart[t] = excl;
    if (t == NC - 1) coarseStart[NC] = excl + v;   // == E
    if (t == 0) rowStart[N] = E;
}

// ---- pass 1: deterministic placement into dense coarse-sorted array ----
// tmp1[pos] = src | (dloc << 17); no global atomics.
__global__ __launch_bounds__(256) void k_part1(const int* __restrict__ src,
                                               const int* __restrict__ dst,
                                               const int* __restrict__ hmat,
                                               const int* __restrict__ coarseStart,
                                               int* __restrict__ tmp1,
                                               int E, int NC) {
    __shared__ int bcnt[MAXC];
    __shared__ int bbase[MAXC];
    int tid = threadIdx.x, blk = blockIdx.x;
    for (int i = tid; i < NC; i += 256) {
        bcnt[i] = 0;
        bbase[i] = coarseStart[i] + hmat[blk * MAXC + i];   // coalesced
    }
    __syncthreads();
    int e0 = blk * EPB, e1 = min(e0 + EPB, E);
    for (int e = e0 + tid; e < e1; e += 256) {
        int s = src[e], d = dst[e];
        int cb = d >> 8;
        int slot = bbase[cb] + atomicAdd(&bcnt[cb], 1);
        tmp1[slot] = s | ((d & 255) << 17);
    }
}

// ---- pass 2 (fused): per-bucket degree->dis/rowStart, then place into CSR ----
// esrc holds BYTE offsets (s*128) for the gather's dword addressing.
__global__ __launch_bounds__(DPT) void k_degplace(const int* __restrict__ tmp1,
                                                  const int* __restrict__ coarseStart,
                                                  float* __restrict__ dis,
                                                  int* __restrict__ rowStart,
                                                  int* __restrict__ esrc, int N) {
    __shared__ int hist[256];
    __shared__ int scn[256];
    __shared__ int cur[256];
    int tid = threadIdx.x;
    int cb = blockIdx.x;
    int node0 = cb << 8;
    const int r0 = coarseStart[cb], r1 = coarseStart[cb + 1];
    if (tid < 256) hist[tid] = 0;
    __syncthreads();
    for (int i = r0 + tid; i < r1; i += DPT)
        atomicAdd(&hist[((unsigned)tmp1[i]) >> 17], 1);
    __syncthreads();
    int v = 0;
    if (tid < 256) { v = hist[tid]; scn[tid] = v; }
    __syncthreads();
    for (int off = 1; off < 256; off <<= 1) {
        int a = 0;
        if (tid < 256 && tid >= off) a = scn[tid - off];
        __syncthreads();
        if (tid < 256) scn[tid] += a;
        __syncthreads();
    }
    if (tid < 256) {
        int myStart = r0 + scn[tid] - v;
        cur[tid] = myStart;
        int node = node0 + tid;
        if (node < N) {
            dis[node] = rsqrtf((float)v + 1.0f);
            rowStart[node] = myStart;
        }
    }
    __syncthreads();
    for (int i = r0 + tid; i < r1; i += DPT) {
        int pk = tmp1[i];
        int dl = ((unsigned)pk) >> 17;
        int pos = atomicAdd(&cur[dl], 1);
        esrc[pos] = (pk & 0x1FFFF) << 7;     // byte offset of bf16 row
    }
}

// ------- MFMA transform: Hbs[N,64] = bf16( (X[N,K] @ W[K,64]) * dis[row] ) -------
template <int K, typename T>
__global__ __launch_bounds__(256) void k_mmx(const T* __restrict__ X,
                                             const float* __restrict__ W,
                                             const float* __restrict__ dis,
                                             unsigned short* __restrict__ Hbs, int N) {
    constexpr int WP = K + 8;
    __shared__ unsigned short Wt[64 * WP];
    const int tid = threadIdx.x;
    for (int i = tid; i < K * 64; i += 256) {
        int k = i >> 6, n = i & 63;
        Wt[n * WP + k] = f2bf(W[i]);
    }
    __syncthreads();
    const int lane = tid & 63;
    const int m16 = lane & 15;
    const int quad = lane >> 4;
    const int rowBase = blockIdx.x * 64 + (tid >> 6) * 16;
    const int rowc = min(rowBase + m16, N - 1);

    f32x4 acc0 = {0.f, 0.f, 0.f, 0.f};
    f32x4 acc1 = acc0, acc2 = acc0, acc3 = acc0;
    const T* xrow = X + (size_t)rowc * K;
#pragma unroll
    for (int k0 = 0; k0 < K; k0 += 32) {
        bf16x8 af;
        if constexpr (sizeof(T) == 4) {
            const float* xp = (const float*)xrow + k0 + quad * 8;
            float4 xa = *(const float4*)xp;
            float4 xb = *(const float4*)(xp + 4);
            af[0] = (short)f2bf(xa.x); af[1] = (short)f2bf(xa.y);
            af[2] = (short)f2bf(xa.z); af[3] = (short)f2bf(xa.w);
            af[4] = (short)f2bf(xb.x); af[5] = (short)f2bf(xb.y);
            af[6] = (short)f2bf(xb.z); af[7] = (short)f2bf(xb.w);
        } else {
            af = *(const bf16x8*)((const unsigned short*)xrow + k0 + quad * 8);
        }
        const unsigned short* wp = &Wt[m16 * WP + k0 + quad * 8];
        bf16x8 b0 = *(const bf16x8*)(wp);
        bf16x8 b1 = *(const bf16x8*)(wp + 16 * WP);
        bf16x8 b2 = *(const bf16x8*)(wp + 32 * WP);
        bf16x8 b3 = *(const bf16x8*)(wp + 48 * WP);
        acc0 = __builtin_amdgcn_mfma_f32_16x16x32_bf16(af, b0, acc0, 0, 0, 0);
        acc1 = __builtin_amdgcn_mfma_f32_16x16x32_bf16(af, b1, acc1, 0, 0, 0);
        acc2 = __builtin_amdgcn_mfma_f32_16x16x32_bf16(af, b2, acc2, 0, 0, 0);
        acc3 = __builtin_amdgcn_mfma_f32_16x16x32_bf16(af, b3, acc3, 0, 0, 0);
    }
#pragma unroll
    for (int reg = 0; reg < 4; ++reg) {
        int r = rowBase + quad * 4 + reg;
        if (r < N) {
            float dsc = dis[r];
            unsigned short* hp = Hbs + (size_t)r * 64 + m16;
            hp[0]  = f2bf(acc0[reg] * dsc);
            hp[16] = f2bf(acc1[reg] * dsc);
            hp[32] = f2bf(acc2[reg] * dsc);
            hp[48] = f2bf(acc3[reg] * dsc);
        }
    }
}

// ------- gather-aggregate: quarter-wave (16 lanes) per node, dwordx2/lane -----
// Each quarter OWNS its node's edge-offset batches: lane c of quarter q loads
// esrc[Rq + bb + c], and all __shfl source indices stay inside the quarter
// [16q, 16q+16). Whenever a quarter is active all 16 of its lanes are active
// (loop bounds are quarter-uniform), so ds_bpermute never reads an inactive
// lane (the round-2 bug: wave-shared batches + divergent loops = undefined
// shfl from exec-masked lanes).
// MODE 1: out = relu row, stored bf16 (feeds bf16 mmx)
// MODE 2: relu row, dot with W3, write colS[i] = dot*dis and out[i] = dot*dis^2 + b3

#define BLO(d) __uint_as_float((d) << 16)
#define BHI(d) __uint_as_float((d) & 0xFFFF0000u)
#define ACC2(A, Q) { A.x += BLO((Q).x); A.y += BHI((Q).x);                     \
                     A.z += BLO((Q).y); A.w += BHI((Q).y); }

template <int MODE>
__global__ __launch_bounds__(256) void k_gather64(const unsigned short* __restrict__ Hbs,
                                                  const int* __restrict__ esrc,
                                                  const int* __restrict__ rowStart,
                                                  const float* __restrict__ dis,
                                                  const float* __restrict__ b,
                                                  unsigned short* __restrict__ outB,
                                                  const float* __restrict__ W3,
                                                  const float* __restrict__ b3,
                                                  float* __restrict__ colS,
                                                  float* __restrict__ outF,
                                                  int N) {
    int lane = threadIdx.x & 63;
    int c = lane & 15;          // 8B chunk of the 128B row
    int sub = lane >> 4;        // quarter index == node slot
    int qb = sub << 4;          // quarter's first lane (shfl base)
    int wave = (blockIdx.x * 256 + threadIdx.x) >> 6;
    int g0 = wave * 4;
    if (g0 >= N) return;
    const char* hb = (const char*)Hbs + c * 8;

    int rb = rowStart[min(g0 + lane, N)];      // wave fully active here
    int Rq  = __shfl(rb, sub, 64);             // this quarter's segment [Rq, Rq1)
    int Rq1 = __shfl(rb, sub + 1, 64);
    int n = g0 + sub;                          // this quarter's node
    int nc = min(n, N - 1);

    // self-loop seed: quarter's own row (h[n]*dis[n]); scaled by dis[n] later
    float4 a;
    {
        uint2 sd = *(const uint2*)(hb + ((size_t)nc << 7));
        a.x = BLO(sd.x); a.y = BHI(sd.x); a.z = BLO(sd.y); a.w = BHI(sd.y);
    }

    unsigned eoff = (Rq + c < Rq1) ? (unsigned)esrc[Rq + c] : 0u;
    for (int bb = Rq; bb < Rq1; bb += 16) {
        int cnt = min(16, Rq1 - bb);
        // prefetch next batch's offsets (independent of this batch's work)
        unsigned eoffN = (bb + 16 + c < Rq1) ? (unsigned)esrc[bb + 16 + c] : 0u;

        int j = 0;
        for (; j + 8 <= cnt; j += 8) {
            unsigned o0 = __shfl(eoff, qb + j + 0, 64);
            unsigned o1 = __shfl(eoff, qb + j + 1, 64);
            unsigned o2 = __shfl(eoff, qb + j + 2, 64);
            unsigned o3 = __shfl(eoff, qb + j + 3, 64);
            unsigned o4 = __shfl(eoff, qb + j + 4, 64);
            unsigned o5 = __shfl(eoff, qb + j + 5, 64);
            unsigned o6 = __shfl(eoff, qb + j + 6, 64);
            unsigned o7 = __shfl(eoff, qb + j + 7, 64);
            uint2 q0 = *(const uint2*)(hb + o0);
            uint2 q1 = *(const uint2*)(hb + o1);
            uint2 q2 = *(const uint2*)(hb + o2);
            uint2 q3 = *(const uint2*)(hb + o3);
            uint2 q4 = *(const uint2*)(hb + o4);
            uint2 q5 = *(const uint2*)(hb + o5);
            uint2 q6 = *(const uint2*)(hb + o6);
            uint2 q7 = *(const uint2*)(hb + o7);
            ACC2(a, q0) ACC2(a, q1) ACC2(a, q2) ACC2(a, q3)
            ACC2(a, q4) ACC2(a, q5) ACC2(a, q6) ACC2(a, q7)
        }
        if (j + 4 <= cnt) {
            unsigned o0 = __shfl(eoff, qb + j + 0, 64);
            unsigned o1 = __shfl(eoff, qb + j + 1, 64);
            unsigned o2 = __shfl(eoff, qb + j + 2, 64);
            unsigned o3 = __shfl(eoff, qb + j + 3, 64);
            uint2 q0 = *(const uint2*)(hb + o0);
            uint2 q1 = *(const uint2*)(hb + o1);
            uint2 q2 = *(const uint2*)(hb + o2);
            uint2 q3 = *(const uint2*)(hb + o3);
            ACC2(a, q0) ACC2(a, q1) ACC2(a, q2) ACC2(a, q3)
            j += 4;
        }
        if (j < cnt) {   // masked remainder 1..3 (slot 0 always valid)
            bool v1 = j + 1 < cnt, v2 = j + 2 < cnt;
            unsigned o0 = __shfl(eoff, qb + j, 64);
            unsigned o1 = __shfl(eoff, v1 ? qb + j + 1 : qb + j, 64);
            unsigned o2 = __shfl(eoff, v2 ? qb + j + 2 : qb + j, 64);
            uint2 q0 = *(const uint2*)(hb + o0);
            uint2 q1 = *(const uint2*)(hb + o1);
            uint2 q2 = *(const uint2*)(hb + o2);
            if (!v1) { q1.x = 0u; q1.y = 0u; }
            if (!v2) { q2.x = 0u; q2.y = 0u; }
            ACC2(a, q0) ACC2(a, q1) ACC2(a, q2)
        }
        eoff = eoffN;
    }

    // epilogue: each quarter finalizes its own node; no cross-sub reduction
    float ds = dis[nc];
    float4 bl = ((const float4*)b)[c];
    float4 v;
    v.x = fmaxf(a.x * ds + bl.x, 0.f);
    v.y = fmaxf(a.y * ds + bl.y, 0.f);
    v.z = fmaxf(a.z * ds + bl.z, 0.f);
    v.w = fmaxf(a.w * ds + bl.w, 0.f);

    if (MODE == 1) {
        uint2 pv;
        pv.x = (unsigned)f2bf(v.x) | ((unsigned)f2bf(v.y) << 16);
        pv.y = (unsigned)f2bf(v.z) | ((unsigned)f2bf(v.w) << 16);
        if (n < N) ((uint2*)outB)[(size_t)n * 16 + c] = pv;   // 512B/wave coalesced
    } else {
        float4 w3 = ((const float4*)W3)[c];
        float t = v.x * w3.x + v.y * w3.y + v.z * w3.z + v.w * w3.w;
        t += __shfl_xor(t, 1, 64);
        t += __shfl_xor(t, 2, 64);
        t += __shfl_xor(t, 4, 64);
        t += __shfl_xor(t, 8, 64);
        if (c == 0 && n < N) {
            colS[n] = t * ds;
            outF[n] = t * ds * ds + b3[0];
        }
    }
}

// layer-3 aggregation: stage block's colS values in LDS (parallel loads),
// then per-node serial sum out of LDS. out[i] += dis[i] * sum colS[esrc>>7]
__global__ __launch_bounds__(256) void k_gather1(const float* __restrict__ colS,
                                                 const int* __restrict__ esrc,
                                                 const int* __restrict__ rowStart,
                                                 const float* __restrict__ dis,
                                                 float* __restrict__ out, int N) {
    __shared__ float ls[G1CAP];
    int tid = threadIdx.x;
    int n0 = blockIdx.x * 256;
    int nEnd = min(n0 + 256, N);
    int r0 = rowStart[n0];
    int r1 = rowStart[nEnd];
    int cnt = r1 - r0;
    if (cnt <= G1CAP) {
        for (int i = tid; i < cnt; i += 256)
            ls[i] = colS[((unsigned)esrc[r0 + i]) >> 7];
        __syncthreads();
        int n = n0 + tid;
        if (n < N) {
            int a = rowStart[n] - r0, bnd = rowStart[n + 1] - r0;
            float acc = 0.0f;
            for (int e = a; e < bnd; ++e) acc += ls[e];
            out[n] += acc * dis[n];
        }
    } else {   // statistically unreachable fallback
        int n = n0 + tid;
        if (n < N) {
            int a = rowStart[n], bnd = rowStart[n + 1];
            float acc = 0.0f;
            for (int e = a; e < bnd; ++e) acc += colS[((unsigned)esrc[e]) >> 7];
            out[n] += acc * dis[n];
        }
    }
}

extern "C" void kernel_launch(void* const* d_in, const int* in_sizes, int n_in,
                              void* d_out, int out_size, void* d_ws, size_t ws_size,
                              hipStream_t stream) {
    const float* x  = (const float*)d_in[0];
    const int*   ei = (const int*)d_in[1];
    const float* W1 = (const float*)d_in[2];
    const float* b1 = (const float*)d_in[3];
    const float* W2 = (const float*)d_in[4];
    const float* b2 = (const float*)d_in[5];
    const float* W3 = (const float*)d_in[6];
    const float* b3 = (const float*)d_in[7];
    float* out = (float*)d_out;

    const int N = in_sizes[0] / IN_DIM;     // 100000
    const int E = in_sizes[1] / 2;          // 1600000
    const int* src = ei;
    const int* dst = ei + E;
    const int NC = (N + 255) >> 8;          // 391 coarse buckets
    const int NBLK = (E + EPB - 1) / EPB;   // 391 partition blocks

    // ---- workspace layout ----
    char* w = (char*)d_ws;
    auto alloc = [&](size_t bytes) {
        char* p = w;
        w += (bytes + 1023) & ~(size_t)1023;
        return p;
    };
    float*          dis        = (float*)alloc((size_t)N * 4);
    unsigned short* Hbs        = (unsigned short*)alloc((size_t)N * 64 * 2);
    unsigned short* Hb1        = (unsigned short*)alloc((size_t)N * 64 * 2);
    float*          colS       = (float*)alloc((size_t)N * 4);
    int*            rowStart   = (int*)alloc((size_t)(N + 1) * 4);
    int*            bktTotal   = (int*)alloc((size_t)MAXC * 4);
    int*            coarseStart= (int*)alloc((size_t)(MAXC + 1) * 4);
    int*            hmat       = (int*)alloc((size_t)MAXB * MAXC * 4);
    int*            esrc       = (int*)alloc((size_t)E * 4);
    int*            tmp1       = (int*)alloc((size_t)E * 4);

    const int NB_N  = (N + 255) / 256;
    const int NB_MX = (N + 63) / 64;                    // MFMA transform blocks
    const int NB_G4 = ((N + 3) / 4 * 64 + 255) / 256;   // 4 nodes per wave

    // ---- deterministic partition (no global atomics, no memset) ----
    k_hist2<<<NBLK, 256, 0, stream>>>(dst, hmat, E, NC);
    k_bktscan<<<NC, 512, 0, stream>>>(hmat, bktTotal, NBLK, NC);
    k_cscan<<<1, 512, 0, stream>>>(bktTotal, coarseStart, rowStart, NC, N, E);
    k_part1<<<NBLK, 256, 0, stream>>>(src, dst, hmat, coarseStart, tmp1, E, NC);
    k_degplace<<<NC, DPT, 0, stream>>>(tmp1, coarseStart, dis, rowStart, esrc, N);

    // ---- layer 1: mmx fp32->bf16, gather -> bf16 rows ----
    k_mmx<IN_DIM, float><<<NB_MX, 256, 0, stream>>>(x, W1, dis, Hbs, N);
    k_gather64<1><<<NB_G4, 256, 0, stream>>>(Hbs, esrc, rowStart, dis, b1,
                                             Hb1, nullptr, nullptr, nullptr, nullptr, N);

    // ---- layer 2: mmx bf16 input, gather fused with W3 dot ----
    k_mmx<HID, unsigned short><<<NB_MX, 256, 0, stream>>>(Hb1, W2, dis, Hbs, N);
    k_gather64<2><<<NB_G4, 256, 0, stream>>>(Hbs, esrc, rowStart, dis, b2,
                                             nullptr, W3, b3, colS, out, N);

    // ---- layer 3 aggregation ----
    k_gather1<<<NB_N, 256, 0, stream>>>(colS, esrc, rowStart, dis, out, N);
}